// Round 9
// baseline (146.949 us; speedup 1.0000x reference)
//
#include <hip/hip_runtime.h>
#include <math.h>

// fab_penalty_ls_curve: curvature penalty over mirrored level-set field.
// R9: 2x2 quad per lane, global-direct (no LDS / no barrier / no conflicts).
// R6/R7/R8 all pinned at 45-50us, busy 40-50%: ~95 issue-slots/pt with only
// 1-2 dependency chains/lane -> trans-chain latency (~80cyc/pt serial) can't
// hide at ~3 waves/SIMD. This round: 14 aligned float2 loads serve 4 points
// (3.5 load-inst/pt), quad shares difference subexpressions via CSE, and 4
// independent rsq/rcp chains per lane quadruple ILP. Unscaled-diff math
// (R8-validated: no SC, 2 trans/pt). Plain partial stores -> finish kernel
// (device-scope atomic finish was R2/R3's 3x regression).
// Mirror-half trick: compute left half only, x2 (verified absmax 0.0).

#define BLOCK_X 256
#define ROWS_PER 16

// Curvature penalty for one interior point from its 13 neighbors, with all
// 1/d powers factored analytically. rd2 = 1/(2d), two_d = 2d.
__device__ __forceinline__ float curve_pt(
    float nn, float nw, float n, float ne,
    float ww, float w, float c, float e, float ee,
    float sw, float s, float se, float ss,
    float rd2, float two_d)
{
    const float pi_d = 3.14159265358979323846f / 1.1f;
    const float u  = s - n;                       // ex / rd2
    const float v  = e - w;                       // ey / rd2
    const float U  = fmaf(-2.0f, c, ss + nn);     // exx / rd2^2
    const float V  = fmaf(-2.0f, c, ee + ww);     // eyy / rd2^2
    const float X2 = 2.0f * ((se - ne) - (sw - nw));   // 2*exy / rd2^2
    const float u2 = u * u, v2 = v * v, uv = u * v;
    float W = u2 * V;
    W = fmaf(v2, U, W);
    W = fmaf(-uv, X2, W);                 // W = u^2 V + v^2 U - 2 u v X
    const float S  = u2 + v2;
    const float rsq = __builtin_amdgcn_rsqf(S);   // S^-0.5
    const float r3  = (rsq * rsq) * rsq;          // S^-1.5
    const float kk  = fabsf(W) * r3;              // |k| / rd2
    const float ae  = fabsf(c);
    const float rc  = __builtin_amdgcn_rcpf(ae);
    const float sq  = S * rsq;                    // sqrt(S)
    const float q   = (rd2 * sq) * rc;            // ev/|eps|  (>0)
    const float iq  = (ae * rsq) * two_d;         // 1/q
    const bool  big = q > 1.0f;
    const float t   = big ? iq : q;
    const float s2  = t * t;
    float p = fmaf(s2, -0.01172120f, 0.05265332f);
    p = fmaf(s2, p, -0.11643287f);
    p = fmaf(s2, p,  0.19354346f);
    p = fmaf(s2, p, -0.33262347f);
    p = fmaf(s2, p,  0.99997726f);
    float at = p * t;
    at = big ? (1.57079632679f - at) : at;        // atan(ev/|eps|)
    const float cc = fmaf(kk * rd2, at, -pi_d);   // |k|*atan - pi_d
    return fmaxf(cc, 0.0f);    // fmax(NaN,0)=0 -> nansum semantics
}

// Generic path: row clamps (one-sided diffs) and column clamp/mirror.
// Used for y-edge blocks and the 2 x-edge lanes of the grid.
__device__ float generic_rows(const float* __restrict__ eps, int Hn, int Wn,
                              int i0, int j, float rd)
{
    const float rd2 = 0.5f * rd;
    const float SC = 1e-12f;
    const float FLOORV = (float)(1e-32 / 6.0);
    const float pi_d = 3.14159265358979323846f / 1.1f;

    const int jm  = (j > 0) ? j - 1 : 0;
    const int jmm = (j > 1) ? j - 2 : 0;
    const int jp = j + 1, jpp = j + 2;
    const int cjp  = (jp  < Wn) ? jp  : (2 * Wn - 1 - jp);   // mirror seam
    const int cjpp = (jpp < Wn) ? jpp : (2 * Wn - 1 - jpp);
    const float syj = (j == 0)  ? rd : rd2;
    const float sym = (jm == 0) ? rd : rd2;
    const float syp = rd2;   // jp never a boundary of the 2W virtual grid

    float acc = 0.0f;
    for (int r = 0; r < ROWS_PER; ++r) {
        const int i = i0 + r;
        if (i >= Hn) break;
        const int im  = (i > 0) ? i - 1 : 0;
        const int ip  = (i < Hn - 1) ? i + 1 : Hn - 1;
        const int imm = (im > 0) ? im - 1 : 0;
        const int ipp = (ip < Hn - 1) ? ip + 1 : Hn - 1;
        const float sxi = (i == 0 || i == Hn - 1) ? rd : rd2;
        const float sxm = (im == 0) ? rd : rd2;
        const float sxp = (ip == Hn - 1) ? rd : rd2;

        const float* rowc  = eps + (size_t)i   * (size_t)Wn;
        const float* rown  = eps + (size_t)im  * (size_t)Wn;
        const float* rows_ = eps + (size_t)ip  * (size_t)Wn;
        const float* rownn = eps + (size_t)imm * (size_t)Wn;
        const float* rowss = eps + (size_t)ipp * (size_t)Wn;

        const float e_c  = rowc[j];
        const float e_n  = rown[j],   e_s  = rows_[j];
        const float e_nn = rownn[j],  e_ss = rowss[j];
        const float e_w  = rowc[jm],  e_e  = rowc[cjp];
        const float e_ww = rowc[jmm], e_ee = rowc[cjpp];
        const float e_nw = rown[jm],  e_ne = rown[cjp];
        const float e_sw = rows_[jm], e_se = rows_[cjp];

        const float ex = fmaf(e_s - e_n, sxi, SC);
        const float ey = fmaf(e_e - e_w, syj, SC);
        float exn = fmaf(e_c - e_nn, sxm, SC);
        float exs = fmaf(e_ss - e_c, sxp, SC);
        if (i == 0)      exn = ex;
        if (i == Hn - 1) exs = ex;
        const float exx = (exs - exn) * sxi;
        float eyw = fmaf(e_c - e_ww, sym, SC);
        const float eye = fmaf(e_ee - e_c, syp, SC);
        if (j == 0) eyw = ey;
        const float eyy = (eye - eyw) * syj;
        const float exy = ((e_se - e_ne) - (e_sw - e_nw)) * (sxi * syj);

        const float t1 = ex * ex;
        const float t2 = ey * ey;
        float num = t1 * eyy;
        num = fmaf(t2, exx, num);
        num = fmaf(-2.0f * (ex * ey), exy, num);

        float ev = __builtin_amdgcn_sqrtf(t1 + t2);
        ev = fmaxf(ev, FLOORV);
        const float rv = __builtin_amdgcn_rcpf(ev);
        const float k  = num * (rv * rv) * rv;
        const float ae = fabsf(e_c);
        const float rc = __builtin_amdgcn_rcpf(ae);
        const float q  = ev * rc;
        const float iq = ae * rv;
        const bool  big = q > 1.0f;
        const float t  = big ? iq : q;
        const float s2 = t * t;
        float p = fmaf(s2, -0.01172120f, 0.05265332f);
        p = fmaf(s2, p, -0.11643287f);
        p = fmaf(s2, p,  0.19354346f);
        p = fmaf(s2, p, -0.33262347f);
        p = fmaf(s2, p,  0.99997726f);
        float at = p * t;
        at = big ? (1.57079632679f - at) : at;
        const float cc = fabsf(k) * at - pi_d;
        acc += fmaxf(cc, 0.0f);
    }
    return acc;
}

__global__ __launch_bounds__(BLOCK_X, 2) void curve_partial_kernel(
    const float* __restrict__ eps, const float* __restrict__ gs,
    double* __restrict__ partial, int Hn, int Wn)
{
    const int tx = threadIdx.x;
    const int jb = blockIdx.x * (2 * BLOCK_X);
    const int p0 = jb + 2 * tx;          // this thread's two columns
    const int p1 = p0 + 1;
    const int i0 = blockIdx.y * ROWS_PER;
    const float d  = gs[0];
    const float rd = 1.0f / d;
    const float rd2 = 0.5f * rd;
    const float two_d = 2.0f * d;

    const bool row_int = (i0 >= 2) && (i0 + ROWS_PER + 2 <= Hn);
    const bool col_int = (p0 >= 2) && (p0 + 3 < Wn);

    float accf = 0.0f;
    if (row_int && col_int) {
        // base points at (row i0, col p0); p0 is even -> float2 aligned
        const float* base = eps + (size_t)i0 * (size_t)Wn + p0;
        const long   w    = (long)Wn;
        #pragma unroll
        for (int t = 0; t < ROWS_PER / 2; ++t) {
            const float* r0  = base + (long)(2 * t) * w;   // quad top row i
            const float* rm2 = r0 - 2 * w;
            const float* rm1 = r0 - w;
            const float* rp1 = r0 + w;
            const float* rp2 = r0 + 2 * w;
            const float* rp3 = r0 + 3 * w;

            // 14 aligned float2 loads serve the 2x2 quad (batched: MLP=14)
            const float2 T  = *(const float2*)(rm2);        // (j,   j+1)
            const float2 N0 = *(const float2*)(rm1 - 2);    // (j-2, j-1)
            const float2 N1 = *(const float2*)(rm1);        // (j,   j+1)
            const float2 N2 = *(const float2*)(rm1 + 2);    // (j+2, j+3)
            const float2 C0 = *(const float2*)(r0 - 2);
            const float2 C1 = *(const float2*)(r0);
            const float2 C2 = *(const float2*)(r0 + 2);
            const float2 S0 = *(const float2*)(rp1 - 2);
            const float2 S1 = *(const float2*)(rp1);
            const float2 S2 = *(const float2*)(rp1 + 2);
            const float2 U0 = *(const float2*)(rp2 - 2);
            const float2 U1 = *(const float2*)(rp2);
            const float2 U2 = *(const float2*)(rp2 + 2);
            const float2 B  = *(const float2*)(rp3);

            // row a = i, col x = j          (CSE merges shared differences)
            accf += curve_pt(T.x,  N0.y, N1.x, N1.y,
                             C0.x, C0.y, C1.x, C1.y, C2.x,
                             S0.y, S1.x, S1.y, U1.x, rd2, two_d);
            // row a, col y = j+1
            accf += curve_pt(T.y,  N1.x, N1.y, N2.x,
                             C0.y, C1.x, C1.y, C2.x, C2.y,
                             S1.x, S1.y, S2.x, U1.y, rd2, two_d);
            // row b = i+1, col x
            accf += curve_pt(N1.x, C0.y, C1.x, C1.y,
                             S0.x, S0.y, S1.x, S1.y, S2.x,
                             U0.y, U1.x, U1.y, B.x,  rd2, two_d);
            // row b, col y
            accf += curve_pt(N1.y, C1.x, C1.y, C2.x,
                             S0.y, S1.x, S1.y, S2.x, S2.y,
                             U1.x, U1.y, U2.x, B.y,  rd2, two_d);
        }
    } else {
        if (p0 < Wn) accf += generic_rows(eps, Hn, Wn, i0, p0, rd);
        if (p1 < Wn) accf += generic_rows(eps, Hn, Wn, i0, p1, rd);
    }

    double acc = (double)accf;
    #pragma unroll
    for (int off = 32; off > 0; off >>= 1)
        acc += __shfl_down(acc, off, 64);
    __shared__ double ldsr[BLOCK_X / 64];
    const int lane = tx & 63, wv = tx >> 6;
    if (lane == 0) ldsr[wv] = acc;
    __syncthreads();
    if (tx == 0) {
        // plain store — NO device-scope atomics
        partial[blockIdx.y * gridDim.x + blockIdx.x] =
            ldsr[0] + ldsr[1] + ldsr[2] + ldsr[3];
    }
}

__global__ __launch_bounds__(256) void curve_finish_kernel(
    const double* __restrict__ partial, int n,
    const float* __restrict__ gs, float* __restrict__ out)
{
    const int tx = threadIdx.x;
    double acc = 0.0;
    for (int idx = tx; idx < n; idx += 256) acc += partial[idx];
    #pragma unroll
    for (int off = 32; off > 0; off >>= 1)
        acc += __shfl_down(acc, off, 64);
    __shared__ double lds[4];
    const int lane = tx & 63, wv = tx >> 6;
    if (lane == 0) lds[wv] = acc;
    __syncthreads();
    if (tx == 0) {
        const double d = (double)gs[0];
        // x2 for the mirrored half; x d^2 for grid_size^2 (ALPHA=1)
        out[0] = (float)((lds[0] + lds[1] + lds[2] + lds[3]) * 2.0 * d * d);
    }
}

extern "C" void kernel_launch(void* const* d_in, const int* in_sizes, int n_in,
                              void* d_out, int out_size, void* d_ws, size_t ws_size,
                              hipStream_t stream) {
    const float* eps = (const float*)d_in[0];
    const float* gs  = (const float*)d_in[1];
    float* out = (float*)d_out;

    const int n = in_sizes[0];
    int Wn = (int)(sqrt((double)n) + 0.5);   // 4096 for 4096x4096
    int Hn = n / Wn;

    const int gx = (Wn + 2 * BLOCK_X - 1) / (2 * BLOCK_X);   // 8
    const int gy = (Hn + ROWS_PER - 1) / ROWS_PER;           // 256
    double* partial = (double*)d_ws;   // gx*gy slots, ALL written every launch

    curve_partial_kernel<<<dim3(gx, gy), BLOCK_X, 0, stream>>>(eps, gs, partial, Hn, Wn);
    curve_finish_kernel<<<1, 256, 0, stream>>>(partial, gx * gy, gs, out);
}